// Round 1
// 236.237 us; speedup vs baseline: 1.0305x; 1.0305x over previous
//
#include <hip/hip_runtime.h>

typedef unsigned short u16;
typedef unsigned int u32;
typedef __bf16 bf16x8 __attribute__((ext_vector_type(8)));
typedef unsigned short ushort8 __attribute__((ext_vector_type(8)));
typedef float floatx4 __attribute__((ext_vector_type(4)));

#define S_LEN 2048
#define NH 32
#define NKV 8
#define HD_ 64
#define LDQ 3072   // qkv row stride: [q 0..2047 | k 2048..2559 | v 2560..3071]

__device__ __forceinline__ u16 f2bf(float f) {
  unsigned u = __builtin_bit_cast(unsigned, f);
  u += 0x7FFF + ((u >> 16) & 1);   // round-to-nearest-even
  return (u16)(u >> 16);
}
__device__ __forceinline__ float bf2f(u16 h) {
  unsigned u = ((unsigned)h) << 16;
  return __builtin_bit_cast(float, u);
}
__device__ __forceinline__ bf16x8 ld8(const u16* p) {
  return __builtin_bit_cast(bf16x8, *(const ushort8*)p);
}
__device__ __forceinline__ floatx4 mfma16(bf16x8 a, bf16x8 b, floatx4 c) {
  return __builtin_amdgcn_mfma_f32_16x16x32_bf16(a, b, c, 0, 0, 0);
}
// two fp32 -> packed bf16 pair (round-half-up via +0x8000, then byte-perm)
__device__ __forceinline__ u32 pk2bf(float a, float b) {
  u32 ua = __builtin_bit_cast(u32, a) + 0x8000u;
  u32 ub = __builtin_bit_cast(u32, b) + 0x8000u;
  return __builtin_amdgcn_perm(ub, ua, 0x07060302);   // [bf(a) | bf(b)<<16]
}

// ---------------- fp32 -> bf16 convert (vectorized) ----------------
__global__ void cvt_kernel(const float* __restrict__ in, u16* __restrict__ out, int n4) {
  int i = blockIdx.x * blockDim.x + threadIdx.x;
  if (i >= n4) return;
  float4 v = ((const float4*)in)[i];
  ((ushort4*)out)[i] = make_ushort4(f2bf(v.x), f2bf(v.y), f2bf(v.z), f2bf(v.w));
}

// ---------------- Double-buffered GEMM: C[M][N] = A[M][K] @ B[N][K]^T (bf16 in) ------------
// TM x TN tile, BK=64, 4 waves (2x2). Single barrier per K-iter: while computing buf p,
// the next tile's global loads (issued at iter start) are ds_written into buf p^1; the
// vmcnt wait for them lands after the full compute phase. LDS chunk-XOR swizzle keeps
// all staging writes and fragment reads <=2 lanes/bank (conflict-free).
// Occupancy note (r1): QKV retiled 128x128 -> 128x96 so grid = 512 blocks = exactly
// 2 blocks/CU (LDS 56KB x2 = 112KB < 160KB). The 128x128 grid was 384 blocks = 1.5/CU:
// 12% occupancy, 1 wave/SIMD on half the chip, barrier drains fully exposed.
template <int TM, int TN, int OUT_BF16>
__global__ __launch_bounds__(256) void gemm_db(
    const u16* __restrict__ A, const u16* __restrict__ B, void* __restrict__ C,
    int ldc, int K, int lda) {
  __shared__ __align__(16) u16 As[2][TM * 64];
  __shared__ __align__(16) u16 Bs[2][TN * 64];
  const int tid = threadIdx.x;
  const int wave = tid >> 6, lane = tid & 63;
  const int quad = lane >> 4, l16 = lane & 15;
  const int bm = blockIdx.y * TM, bn = blockIdx.x * TN;
  const int wr = (wave >> 1) * (TM / 2), wc = (wave & 1) * (TN / 2);
  constexpr int MI = TM / 32, NI = TN / 32;
  const int crow = tid >> 3, col8 = tid & 7;     // staging: row base, 8-elem col chunk

  size_t aoff[MI], boff[NI];
#pragma unroll
  for (int j = 0; j < MI; j++) aoff[j] = (size_t)(bm + crow + j * 32) * lda + col8 * 8;
#pragma unroll
  for (int j = 0; j < NI; j++) boff[j] = (size_t)(bn + crow + j * 32) * K + col8 * 8;

  ushort8 a8[MI], b8[NI];
  auto load_tiles = [&](int k0) {
#pragma unroll
    for (int j = 0; j < MI; j++) a8[j] = *(const ushort8*)(A + aoff[j] + k0);
#pragma unroll
    for (int j = 0; j < NI; j++) b8[j] = *(const ushort8*)(B + boff[j] + k0);
  };
  auto write_tiles = [&](int p) {
#pragma unroll
    for (int j = 0; j < MI; j++) {
      const int row = crow + j * 32;
      *(ushort8*)&As[p][row * 64 + ((col8 ^ (row & 7)) * 8)] = a8[j];
    }
#pragma unroll
    for (int j = 0; j < NI; j++) {
      const int row = crow + j * 32;
      *(ushort8*)&Bs[p][row * 64 + ((col8 ^ (row & 7)) * 8)] = b8[j];
    }
  };

  floatx4 acc[MI][NI] = {};
  load_tiles(0);
  write_tiles(0);
  __syncthreads();
  int p = 0;
  for (int k0 = 0; k0 < K; k0 += 64) {
    const bool more = (k0 + 64 < K);
    if (more) load_tiles(k0 + 64);               // prefetch next tile (covered by compute)
#pragma unroll
    for (int kh = 0; kh < 2; kh++) {
      bf16x8 af[MI], bfr[NI];
#pragma unroll
      for (int mi = 0; mi < MI; mi++) {
        const int row = wr + mi * 16 + l16;
        af[mi] = ld8(&As[p][row * 64 + (((kh * 4 + quad) ^ (row & 7)) * 8)]);
      }
#pragma unroll
      for (int ni = 0; ni < NI; ni++) {
        const int row = wc + ni * 16 + l16;
        bfr[ni] = ld8(&Bs[p][row * 64 + (((kh * 4 + quad) ^ (row & 7)) * 8)]);
      }
#pragma unroll
      for (int mi = 0; mi < MI; mi++)
#pragma unroll
        for (int ni = 0; ni < NI; ni++)
          acc[mi][ni] = mfma16(af[mi], bfr[ni], acc[mi][ni]);
    }
    if (more) {
      write_tiles(p ^ 1);                        // vmcnt wait lands here, post-compute
      __syncthreads();                           // one barrier per iter
      p ^= 1;
    }
  }

#pragma unroll
  for (int mi = 0; mi < MI; mi++)
#pragma unroll
    for (int ni = 0; ni < NI; ni++)
#pragma unroll
      for (int r = 0; r < 4; r++) {
        const int row = bm + wr + mi * 16 + quad * 4 + r;   // C/D: row=(lane>>4)*4+reg
        const int col = bn + wc + ni * 16 + l16;            //      col=lane&15
        if (OUT_BF16) ((u16*)C)[(size_t)row * ldc + col] = f2bf(acc[mi][ni][r]);
        else          ((float*)C)[(size_t)row * ldc + col] = acc[mi][ni][r];
      }
}

// ---------------- RoPE in-place on bf16, rows of `row_stride`, nheads = 1<<h_bits ----------------
__global__ void rope_kernel(u16* __restrict__ qk, const float* __restrict__ fc, int h_bits,
                            int row_stride, float scale) {
  int idx = blockIdx.x * blockDim.x + threadIdx.x;   // over S * nheads * 32 pairs
  int d = idx & 31;
  int t = idx >> 5;
  int hh = t & ((1 << h_bits) - 1);
  int s = t >> h_bits;
  float c  = fc[s * 64 + d * 2];
  float sn = fc[s * 64 + d * 2 + 1];
  size_t base = (size_t)s * row_stride + hh * 64 + d * 2;
  float x0 = bf2f(qk[base]), x1 = bf2f(qk[base + 1]);
  qk[base]     = f2bf((x0 * c - x1 * sn) * scale);
  qk[base + 1] = f2bf((x0 * sn + x1 * c) * scale);
}

// ---------------- V transpose: qkv[s][2560 + g*64+hd] -> vT[(g*64+hd)][s] ----------------
__global__ void transpose_v(const u16* __restrict__ qkv, u16* __restrict__ vT) {
  int idx = blockIdx.x * blockDim.x + threadIdx.x;   // over KV*HD*S
  int s = idx & (S_LEN - 1);
  int t = idx >> 11;                                 // g*64+hd
  vT[idx] = qkv[(size_t)s * LDQ + 2560 + t];
}

// ---------------- Flash attention (causal, GQA), LDS-staged K/V, no-max softmax ------------
// block = (head h, 64 q rows); 4 waves x 16 q rows; BK=64 key tiles.
// qkv READ-ONLY (q + k cols, stride LDQ); output to separate o buffer (stride 2048).
// P = exp2(s'), log2e/8 folded into Q. l via MFMA ones-row.
__global__ __launch_bounds__(256) void attn_kernel(const u16* qkv, const u16* __restrict__ vT,
                                                   u16* __restrict__ o) {
  __shared__ __align__(16) u16 Ks[64 * 72];      // [key][hd], stride 72
  __shared__ __align__(16) u16 Vs[64 * 72];      // [hd][key], stride 72
  __shared__ __align__(16) u16 pS[4][16 * 72];   // per-wave P^T scratch [q][key], stride 72
  const int h = blockIdx.x;
  const int qt = (h & 1) ? (31 - (int)blockIdx.y) : (int)blockIdx.y;  // causal load-balance swizzle
  const int g = h >> 2;                          // kv head
  const int tid = threadIdx.x;
  const int wave = tid >> 6, lane = tid & 63;
  const int quad = lane >> 4, l16 = lane & 15;
  const int qglob = qt * 64 + wave * 16 + l16;   // this lane's q column

  const size_t qoff = (size_t)qglob * LDQ + h * HD_;
  bf16x8 qf0 = ld8(qkv + qoff + quad * 8);       // B-frag: n=q, k=hd (pre-scaled log2e/8)
  bf16x8 qf1 = ld8(qkv + qoff + 32 + quad * 8);

  const ushort8 ones_u = {0x3F80, 0x3F80, 0x3F80, 0x3F80, 0x3F80, 0x3F80, 0x3F80, 0x3F80};
  const bf16x8 onesA = __builtin_bit_cast(bf16x8, ones_u);

  // staging: 512 chunks of 16B per tile; thread t owns chunks {t, t+256}
  const int r0 = tid >> 3,         o0 = (tid & 7) * 8;          // rows 0..31
  const int r1 = (tid + 256) >> 3, o1 = o0;                     // rows 32..63
  const u16* ksrc = qkv + 2048 + g * HD_;                       // row stride LDQ
  const u16* vsrc = vT + (size_t)g * HD_ * S_LEN;               // row stride S_LEN

  ushort8 kp0 = *(const ushort8*)(ksrc + (size_t)r0 * LDQ + o0);
  ushort8 kp1 = *(const ushort8*)(ksrc + (size_t)r1 * LDQ + o1);
  ushort8 vp0 = *(const ushort8*)(vsrc + (size_t)r0 * S_LEN + o0);
  ushort8 vp1 = *(const ushort8*)(vsrc + (size_t)r1 * S_LEN + o1);

  floatx4 Ofrag[4] = {};                         // O^T: row=hd(nt*16+quad*4+r), col=q(l16)
  floatx4 lacc = {};                             // l (all 4 regs identical per lane)
  u16* myP = &pS[wave][0];

  for (int kt = 0; kt <= qt; kt++) {
    const int kbase = kt * 64;
    *(ushort8*)&Ks[r0 * 72 + o0] = kp0;
    *(ushort8*)&Ks[r1 * 72 + o1] = kp1;
    *(ushort8*)&Vs[r0 * 72 + o0] = vp0;
    *(ushort8*)&Vs[r1 * 72 + o1] = vp1;
    __syncthreads();
    if (kt < qt) {                               // prefetch next tile (overlaps compute below)
      const int nb = kbase + 64;
      kp0 = *(const ushort8*)(ksrc + (size_t)(nb + r0) * LDQ + o0);
      kp1 = *(const ushort8*)(ksrc + (size_t)(nb + r1) * LDQ + o1);
      vp0 = *(const ushort8*)(vsrc + (size_t)r0 * S_LEN + nb + o0);
      vp1 = *(const ushort8*)(vsrc + (size_t)r1 * S_LEN + nb + o1);
    }
    // ---- S^T = K*Q^T : 4 sub-tiles of 16 keys ----
    floatx4 sf[4];
#pragma unroll
    for (int sub = 0; sub < 4; sub++) {
      const u16* kb = &Ks[(sub * 16 + l16) * 72];
      floatx4 s = {};
      s = mfma16(ld8(kb + quad * 8), qf0, s);    // A-frag: m=key, k=hd
      s = mfma16(ld8(kb + 32 + quad * 8), qf1, s);
      sf[sub] = s;
    }
    if (kt == qt) {                              // diagonal tile: mask key > q
#pragma unroll
      for (int sub = 0; sub < 4; sub++)
#pragma unroll
        for (int r = 0; r < 4; r++)
          if (kbase + sub * 16 + quad * 4 + r > qglob) sf[sub][r] = -INFINITY;
    }
    // ---- P = exp2(s'), pack to bf16 pairs ----
    u32 pk[4][2];
#pragma unroll
    for (int sub = 0; sub < 4; sub++)
#pragma unroll
      for (int w = 0; w < 2; w++) {
        float p0 = __builtin_amdgcn_exp2f(sf[sub][2 * w]);
        float p1 = __builtin_amdgcn_exp2f(sf[sub][2 * w + 1]);
        pk[sub][w] = pk2bf(p0, p1);
      }
    // ---- V frags from LDS ----
    bf16x8 vf[4][2];
#pragma unroll
    for (int nt = 0; nt < 4; nt++) {
      const u16* vb = &Vs[(nt * 16 + l16) * 72 + quad * 8];
      vf[nt][0] = ld8(vb);
      vf[nt][1] = ld8(vb + 32);
    }
    // ---- P^T to per-wave LDS scratch ----
#pragma unroll
    for (int sub = 0; sub < 4; sub++)
#pragma unroll
      for (int w = 0; w < 2; w++)
        *(u32*)&myP[l16 * 72 + sub * 16 + quad * 4 + 2 * w] = pk[sub][w];
    asm volatile("s_waitcnt lgkmcnt(0)" ::: "memory");  // wave-local LDS write->read fence
    bf16x8 pf0 = ld8(&myP[l16 * 72 + quad * 8]);        // B-frag: n=q, k=key(0..31)
    bf16x8 pf1 = ld8(&myP[l16 * 72 + 32 + quad * 8]);   //                 key(32..63)
    // ---- O^T += V^T * P^T ; l += ones * P^T (matrix pipe) ----
#pragma unroll
    for (int nt = 0; nt < 4; nt++) {
      Ofrag[nt] = mfma16(vf[nt][0], pf0, Ofrag[nt]);
      Ofrag[nt] = mfma16(vf[nt][1], pf1, Ofrag[nt]);
    }
    lacc = mfma16(onesA, pf0, lacc);
    lacc = mfma16(onesA, pf1, lacc);
    __syncthreads();                             // protect Ks/Vs before next staging
  }

  const float inv = 1.0f / lacc[0];
  const size_t ooff = (size_t)qglob * 2048 + h * HD_;
#pragma unroll
  for (int nt = 0; nt < 4; nt++)
#pragma unroll
    for (int r = 0; r < 4; r++) {
      int hd = nt * 16 + quad * 4 + r;
      o[ooff + hd] = f2bf(Ofrag[nt][r] * inv);
    }
}

extern "C" void kernel_launch(void* const* d_in, const int* in_sizes, int n_in,
                              void* d_out, int out_size, void* d_ws, size_t ws_size,
                              hipStream_t stream) {
  const float* x  = (const float*)d_in[0];
  const float* fc = (const float*)d_in[1];
  const float* wq = (const float*)d_in[2];
  const float* wk = (const float*)d_in[3];
  const float* wv = (const float*)d_in[4];
  const float* wo = (const float*)d_in[5];
  float* out = (float*)d_out;

  // Workspace (30 MB — r3-proven size). Lifetimes:
  //   [0,12)MB  qkv bf16: 2048 x 3072 (q|k|v), written by QKV gemm, read-only after rope
  //   [12,24)MB wb bf16: wq|wk|wv (3072 x 2048) — dead after QKV gemm
  //   [12,14)MB vT bf16 (after wb dead)
  //   [14,22)MB wob bf16 (cvt'd after QKV gemm)
  //   [22,30)MB ob bf16: attention output
  // x bf16 (8 MB) lives in d_out (16.8 MB) — overwritten by the final O-GEMM.
  char* ws = (char*)d_ws;
  const size_t MB = 1024 * 1024;
  u16* qkv = (u16*)(ws);
  u16* wb  = (u16*)(ws + 12 * MB);
  u16* vTb = (u16*)(ws + 12 * MB);
  u16* wob = (u16*)(ws + 14 * MB);
  u16* ob  = (u16*)(ws + 22 * MB);
  u16* xb  = (u16*)d_out;
  (void)ws_size; (void)n_in; (void)in_sizes; (void)out_size;

  // 1) x, wq|wk|wv -> bf16
  cvt_kernel<<<4096, 256, 0, stream>>>(x,  xb, 1048576);
  cvt_kernel<<<4096, 256, 0, stream>>>(wq, wb, 1048576);
  cvt_kernel<<<1024, 256, 0, stream>>>(wk, wb + (size_t)2048 * 2048, 262144);
  cvt_kernel<<<1024, 256, 0, stream>>>(wv, wb + (size_t)2560 * 2048, 262144);
  // 2) fused QKV projection (128x96 tile -> 512 blocks = 2/CU exactly, all-bf16, dbuf)
  gemm_db<128, 96, 1><<<dim3(32, 16), 256, 0, stream>>>(xb, wb, qkv, LDQ, 2048, 2048);
  // 3) wo -> bf16 (wb region dead now)
  cvt_kernel<<<4096, 256, 0, stream>>>(wo, wob, 1048576);
  // 4) RoPE: q pre-scaled by log2e/sqrt(HD); k unscaled
  rope_kernel<<<8192, 256, 0, stream>>>(qkv, fc, 5, LDQ, 0.18033688f);
  rope_kernel<<<2048, 256, 0, stream>>>(qkv + 2048, fc, 3, LDQ, 1.0f);
  // 5) V transpose
  transpose_v<<<4096, 256, 0, stream>>>(qkv, vTb);
  // 6) causal GQA flash attention -> ob
  attn_kernel<<<dim3(NH, S_LEN / 64), 256, 0, stream>>>(qkv, vTb, ob);
  // 7) output projection (128x64, all-bf16, dbuf, fp32 out) — overwrites xb scratch
  gemm_db<128, 64, 0><<<dim3(32, 16), 256, 0, stream>>>(ob, wob, out, 2048, 2048, 2048);
}

// Round 2
// 233.812 us; speedup vs baseline: 1.0412x; 1.0104x over previous
//
#include <hip/hip_runtime.h>

typedef unsigned short u16;
typedef unsigned int u32;
typedef __bf16 bf16x8 __attribute__((ext_vector_type(8)));
typedef unsigned short ushort8 __attribute__((ext_vector_type(8)));
typedef float floatx4 __attribute__((ext_vector_type(4)));
typedef u32 u32x2 __attribute__((ext_vector_type(2)));

#define S_LEN 2048
#define NH 32
#define NKV 8
#define HD_ 64
#define LDQ 3072   // qkv row stride: [q 0..2047 | k 2048..2559 | v 2560..3071]

__device__ __forceinline__ u16 f2bf(float f) {
  unsigned u = __builtin_bit_cast(unsigned, f);
  u += 0x7FFF + ((u >> 16) & 1);   // round-to-nearest-even
  return (u16)(u >> 16);
}
__device__ __forceinline__ float bf2f(u16 h) {
  unsigned u = ((unsigned)h) << 16;
  return __builtin_bit_cast(float, u);
}
__device__ __forceinline__ bf16x8 ld8(const u16* p) {
  return __builtin_bit_cast(bf16x8, *(const ushort8*)p);
}
__device__ __forceinline__ floatx4 mfma16(bf16x8 a, bf16x8 b, floatx4 c) {
  return __builtin_amdgcn_mfma_f32_16x16x32_bf16(a, b, c, 0, 0, 0);
}
// two fp32 -> packed bf16 pair (round-half-up via +0x8000, then byte-perm)
__device__ __forceinline__ u32 pk2bf(float a, float b) {
  u32 ua = __builtin_bit_cast(u32, a) + 0x8000u;
  u32 ub = __builtin_bit_cast(u32, b) + 0x8000u;
  return __builtin_amdgcn_perm(ub, ua, 0x07060302);   // [bf(a) | bf(b)<<16]
}

// ---------------- fp32 -> bf16 convert (vectorized) ----------------
__global__ void cvt_kernel(const float* __restrict__ in, u16* __restrict__ out, int n4) {
  int i = blockIdx.x * blockDim.x + threadIdx.x;
  if (i >= n4) return;
  float4 v = ((const float4*)in)[i];
  ((ushort4*)out)[i] = make_ushort4(f2bf(v.x), f2bf(v.y), f2bf(v.z), f2bf(v.w));
}

// ---------------- Double-buffered GEMM: C[M][N] = A[M][K] @ B[N][K]^T (bf16 in) ------------
// TM x TN tile, BK=64, 4 waves (2x2). Single barrier per K-iter: while computing buf p,
// the next tile's global loads (issued at iter start) are ds_written into buf p^1; the
// vmcnt wait for them lands after the full compute phase. LDS chunk-XOR swizzle keeps
// all staging writes and fragment reads <=2 lanes/bank (conflict-free).
// Occupancy note (r1): QKV retiled 128x128 -> 128x96 so grid = 512 blocks = exactly
// 2 blocks/CU (LDS 56KB x2 = 112KB < 160KB). The 128x128 grid was 384 blocks = 1.5/CU:
// 12% occupancy, 1 wave/SIMD on half the chip, barrier drains fully exposed.
template <int TM, int TN, int OUT_BF16>
__global__ __launch_bounds__(256) void gemm_db(
    const u16* __restrict__ A, const u16* __restrict__ B, void* __restrict__ C,
    int ldc, int K, int lda) {
  __shared__ __align__(16) u16 As[2][TM * 64];
  __shared__ __align__(16) u16 Bs[2][TN * 64];
  const int tid = threadIdx.x;
  const int wave = tid >> 6, lane = tid & 63;
  const int quad = lane >> 4, l16 = lane & 15;
  const int bm = blockIdx.y * TM, bn = blockIdx.x * TN;
  const int wr = (wave >> 1) * (TM / 2), wc = (wave & 1) * (TN / 2);
  constexpr int MI = TM / 32, NI = TN / 32;
  const int crow = tid >> 3, col8 = tid & 7;     // staging: row base, 8-elem col chunk

  size_t aoff[MI], boff[NI];
#pragma unroll
  for (int j = 0; j < MI; j++) aoff[j] = (size_t)(bm + crow + j * 32) * lda + col8 * 8;
#pragma unroll
  for (int j = 0; j < NI; j++) boff[j] = (size_t)(bn + crow + j * 32) * K + col8 * 8;

  ushort8 a8[MI], b8[NI];
  auto load_tiles = [&](int k0) {
#pragma unroll
    for (int j = 0; j < MI; j++) a8[j] = *(const ushort8*)(A + aoff[j] + k0);
#pragma unroll
    for (int j = 0; j < NI; j++) b8[j] = *(const ushort8*)(B + boff[j] + k0);
  };
  auto write_tiles = [&](int p) {
#pragma unroll
    for (int j = 0; j < MI; j++) {
      const int row = crow + j * 32;
      *(ushort8*)&As[p][row * 64 + ((col8 ^ (row & 7)) * 8)] = a8[j];
    }
#pragma unroll
    for (int j = 0; j < NI; j++) {
      const int row = crow + j * 32;
      *(ushort8*)&Bs[p][row * 64 + ((col8 ^ (row & 7)) * 8)] = b8[j];
    }
  };

  floatx4 acc[MI][NI] = {};
  load_tiles(0);
  write_tiles(0);
  __syncthreads();
  int p = 0;
  for (int k0 = 0; k0 < K; k0 += 64) {
    const bool more = (k0 + 64 < K);
    if (more) load_tiles(k0 + 64);               // prefetch next tile (covered by compute)
#pragma unroll
    for (int kh = 0; kh < 2; kh++) {
      bf16x8 af[MI], bfr[NI];
#pragma unroll
      for (int mi = 0; mi < MI; mi++) {
        const int row = wr + mi * 16 + l16;
        af[mi] = ld8(&As[p][row * 64 + (((kh * 4 + quad) ^ (row & 7)) * 8)]);
      }
#pragma unroll
      for (int ni = 0; ni < NI; ni++) {
        const int row = wc + ni * 16 + l16;
        bfr[ni] = ld8(&Bs[p][row * 64 + (((kh * 4 + quad) ^ (row & 7)) * 8)]);
      }
#pragma unroll
      for (int mi = 0; mi < MI; mi++)
#pragma unroll
        for (int ni = 0; ni < NI; ni++)
          acc[mi][ni] = mfma16(af[mi], bfr[ni], acc[mi][ni]);
    }
    if (more) {
      write_tiles(p ^ 1);                        // vmcnt wait lands here, post-compute
      __syncthreads();                           // one barrier per iter
      p ^= 1;
    }
  }

#pragma unroll
  for (int mi = 0; mi < MI; mi++)
#pragma unroll
    for (int ni = 0; ni < NI; ni++)
#pragma unroll
      for (int r = 0; r < 4; r++) {
        const int row = bm + wr + mi * 16 + quad * 4 + r;   // C/D: row=(lane>>4)*4+reg
        const int col = bn + wc + ni * 16 + l16;            //      col=lane&15
        if (OUT_BF16) ((u16*)C)[(size_t)row * ldc + col] = f2bf(acc[mi][ni][r]);
        else          ((float*)C)[(size_t)row * ldc + col] = acc[mi][ni][r];
      }
}

// ---------------- RoPE in-place on bf16, rows of `row_stride`, nheads = 1<<h_bits ----------------
__global__ void rope_kernel(u16* __restrict__ qk, const float* __restrict__ fc, int h_bits,
                            int row_stride, float scale) {
  int idx = blockIdx.x * blockDim.x + threadIdx.x;   // over S * nheads * 32 pairs
  int d = idx & 31;
  int t = idx >> 5;
  int hh = t & ((1 << h_bits) - 1);
  int s = t >> h_bits;
  float c  = fc[s * 64 + d * 2];
  float sn = fc[s * 64 + d * 2 + 1];
  size_t base = (size_t)s * row_stride + hh * 64 + d * 2;
  float x0 = bf2f(qk[base]), x1 = bf2f(qk[base + 1]);
  qk[base]     = f2bf((x0 * c - x1 * sn) * scale);
  qk[base + 1] = f2bf((x0 * sn + x1 * c) * scale);
}

// ---------------- V transpose: qkv[s][2560 + g*64+hd] -> vT[(g*64+hd)][s] ----------------
__global__ void transpose_v(const u16* __restrict__ qkv, u16* __restrict__ vT) {
  int idx = blockIdx.x * blockDim.x + threadIdx.x;   // over KV*HD*S
  int s = idx & (S_LEN - 1);
  int t = idx >> 11;                                 // g*64+hd
  vT[idx] = qkv[(size_t)s * LDQ + 2560 + t];
}

// ---------------- Flash attention (causal, GQA), LDS-staged K/V, no-max softmax ------------
// r2 rebalance: block = (head h, pair p) processes q-tiles p and 31-p SEQUENTIALLY ->
// 512 blocks, each EXACTLY 33 K-iters (uniform). 2 blocks/CU deterministic, no dispatch
// tail (the old 1..32-iter spread let unlucky CUs serialize ~4 heavy blocks = the whole
// 48us). 4 waves x 16 q rows; BK=64 key tiles; P^T scratch stored as ds_write_b64
// (was 8x u32 with 4-way bank aliasing -> 4x b64, 2-way max).
__global__ __launch_bounds__(256) void attn_kernel(const u16* qkv, const u16* __restrict__ vT,
                                                   u16* __restrict__ o) {
  __shared__ __align__(16) u16 Ks[64 * 72];      // [key][hd], stride 72
  __shared__ __align__(16) u16 Vs[64 * 72];      // [hd][key], stride 72
  __shared__ __align__(16) u16 pS[4][16 * 72];   // per-wave P^T scratch [q][key], stride 72
  const int h = blockIdx.x;
  const int g = h >> 2;                          // kv head
  const int tid = threadIdx.x;
  const int wave = tid >> 6, lane = tid & 63;
  const int quad = lane >> 4, l16 = lane & 15;
  const int qtA = (int)blockIdx.y;               // 0..15
  const int qtB = 31 - qtA;                      // 16..31

  const ushort8 ones_u = {0x3F80, 0x3F80, 0x3F80, 0x3F80, 0x3F80, 0x3F80, 0x3F80, 0x3F80};
  const bf16x8 onesA = __builtin_bit_cast(bf16x8, ones_u);

  // both phases' Q frags up front (global loads, latency hidden behind phase A)
  const int qrow = wave * 16 + l16;
  const size_t qoffA = (size_t)(qtA * 64 + qrow) * LDQ + h * HD_;
  const size_t qoffB = (size_t)(qtB * 64 + qrow) * LDQ + h * HD_;
  bf16x8 qfA0 = ld8(qkv + qoffA + quad * 8);     // B-frag: n=q, k=hd (pre-scaled log2e/8)
  bf16x8 qfA1 = ld8(qkv + qoffA + 32 + quad * 8);
  bf16x8 qfB0 = ld8(qkv + qoffB + quad * 8);
  bf16x8 qfB1 = ld8(qkv + qoffB + 32 + quad * 8);

  // staging: 512 chunks of 16B per tile; thread t owns chunks {t, t+256}
  const int r0 = tid >> 3,         o0 = (tid & 7) * 8;          // rows 0..31
  const int r1 = (tid + 256) >> 3, o1 = o0;                     // rows 32..63
  const u16* ksrc = qkv + 2048 + g * HD_;                       // row stride LDQ
  const u16* vsrc = vT + (size_t)g * HD_ * S_LEN;               // row stride S_LEN

  ushort8 kp0 = *(const ushort8*)(ksrc + (size_t)r0 * LDQ + o0);
  ushort8 kp1 = *(const ushort8*)(ksrc + (size_t)r1 * LDQ + o1);
  ushort8 vp0 = *(const ushort8*)(vsrc + (size_t)r0 * S_LEN + o0);
  ushort8 vp1 = *(const ushort8*)(vsrc + (size_t)r1 * S_LEN + o1);

  u16* myP = &pS[wave][0];

  for (int ph = 0; ph < 2; ph++) {
    const int qt = ph ? qtB : qtA;
    const int qglob = qt * 64 + qrow;            // this lane's q column
    const bf16x8 qf0 = ph ? qfB0 : qfA0;
    const bf16x8 qf1 = ph ? qfB1 : qfA1;
    floatx4 Ofrag[4] = {};                       // O^T: row=hd(nt*16+quad*4+r), col=q(l16)
    floatx4 lacc = {};                           // l (all 4 regs identical per lane)

    for (int kt = 0; kt <= qt; kt++) {
      const int kbase = kt * 64;
      *(ushort8*)&Ks[r0 * 72 + o0] = kp0;
      *(ushort8*)&Ks[r1 * 72 + o1] = kp1;
      *(ushort8*)&Vs[r0 * 72 + o0] = vp0;
      *(ushort8*)&Vs[r1 * 72 + o1] = vp1;
      __syncthreads();
      const bool last = (kt == qt);
      if (!last || ph == 0) {                    // prefetch next tile (or phase B's kt=0)
        const int nb = last ? 0 : kbase + 64;
        kp0 = *(const ushort8*)(ksrc + (size_t)(nb + r0) * LDQ + o0);
        kp1 = *(const ushort8*)(ksrc + (size_t)(nb + r1) * LDQ + o1);
        vp0 = *(const ushort8*)(vsrc + (size_t)r0 * S_LEN + nb + o0);
        vp1 = *(const ushort8*)(vsrc + (size_t)r1 * S_LEN + nb + o1);
      }
      // ---- S^T = K*Q^T : 4 sub-tiles of 16 keys ----
      floatx4 sf[4];
#pragma unroll
      for (int sub = 0; sub < 4; sub++) {
        const u16* kb = &Ks[(sub * 16 + l16) * 72];
        floatx4 s = {};
        s = mfma16(ld8(kb + quad * 8), qf0, s);  // A-frag: m=key, k=hd
        s = mfma16(ld8(kb + 32 + quad * 8), qf1, s);
        sf[sub] = s;
      }
      if (last) {                                // diagonal tile: mask key > q
#pragma unroll
        for (int sub = 0; sub < 4; sub++)
#pragma unroll
          for (int r = 0; r < 4; r++)
            if (kbase + sub * 16 + quad * 4 + r > qglob) sf[sub][r] = -INFINITY;
      }
      // ---- P = exp2(s'), pack to bf16 pairs ----
      u32x2 pk[4];
#pragma unroll
      for (int sub = 0; sub < 4; sub++) {
        float p0 = __builtin_amdgcn_exp2f(sf[sub][0]);
        float p1 = __builtin_amdgcn_exp2f(sf[sub][1]);
        float p2 = __builtin_amdgcn_exp2f(sf[sub][2]);
        float p3 = __builtin_amdgcn_exp2f(sf[sub][3]);
        pk[sub].x = pk2bf(p0, p1);
        pk[sub].y = pk2bf(p2, p3);
      }
      // ---- V frags from LDS ----
      bf16x8 vf[4][2];
#pragma unroll
      for (int nt = 0; nt < 4; nt++) {
        const u16* vb = &Vs[(nt * 16 + l16) * 72 + quad * 8];
        vf[nt][0] = ld8(vb);
        vf[nt][1] = ld8(vb + 32);
      }
      // ---- P^T to per-wave LDS scratch (b64 stores, 2-way max) ----
#pragma unroll
      for (int sub = 0; sub < 4; sub++)
        *(u32x2*)&myP[l16 * 72 + sub * 16 + quad * 4] = pk[sub];
      asm volatile("s_waitcnt lgkmcnt(0)" ::: "memory");  // wave-local LDS write->read fence
      bf16x8 pf0 = ld8(&myP[l16 * 72 + quad * 8]);        // B-frag: n=q, k=key(0..31)
      bf16x8 pf1 = ld8(&myP[l16 * 72 + 32 + quad * 8]);   //                 key(32..63)
      // ---- O^T += V^T * P^T ; l += ones * P^T (matrix pipe) ----
#pragma unroll
      for (int nt = 0; nt < 4; nt++) {
        Ofrag[nt] = mfma16(vf[nt][0], pf0, Ofrag[nt]);
        Ofrag[nt] = mfma16(vf[nt][1], pf1, Ofrag[nt]);
      }
      lacc = mfma16(onesA, pf0, lacc);
      lacc = mfma16(onesA, pf1, lacc);
      __syncthreads();                           // protect Ks/Vs before next staging
    }

    const float inv = 1.0f / lacc[0];
    const size_t ooff = (size_t)qglob * 2048 + h * HD_;
#pragma unroll
    for (int nt = 0; nt < 4; nt++)
#pragma unroll
      for (int r = 0; r < 4; r++) {
        int hd = nt * 16 + quad * 4 + r;
        o[ooff + hd] = f2bf(Ofrag[nt][r] * inv);
      }
  }
}

extern "C" void kernel_launch(void* const* d_in, const int* in_sizes, int n_in,
                              void* d_out, int out_size, void* d_ws, size_t ws_size,
                              hipStream_t stream) {
  const float* x  = (const float*)d_in[0];
  const float* fc = (const float*)d_in[1];
  const float* wq = (const float*)d_in[2];
  const float* wk = (const float*)d_in[3];
  const float* wv = (const float*)d_in[4];
  const float* wo = (const float*)d_in[5];
  float* out = (float*)d_out;

  // Workspace (30 MB — r3-proven size). Lifetimes:
  //   [0,12)MB  qkv bf16: 2048 x 3072 (q|k|v), written by QKV gemm, read-only after rope
  //   [12,24)MB wb bf16: wq|wk|wv (3072 x 2048) — dead after QKV gemm
  //   [12,14)MB vT bf16 (after wb dead)
  //   [14,22)MB wob bf16 (cvt'd after QKV gemm)
  //   [22,30)MB ob bf16: attention output
  // x bf16 (8 MB) lives in d_out (16.8 MB) — overwritten by the final O-GEMM.
  char* ws = (char*)d_ws;
  const size_t MB = 1024 * 1024;
  u16* qkv = (u16*)(ws);
  u16* wb  = (u16*)(ws + 12 * MB);
  u16* vTb = (u16*)(ws + 12 * MB);
  u16* wob = (u16*)(ws + 14 * MB);
  u16* ob  = (u16*)(ws + 22 * MB);
  u16* xb  = (u16*)d_out;
  (void)ws_size; (void)n_in; (void)in_sizes; (void)out_size;

  // 1) x, wq|wk|wv -> bf16
  cvt_kernel<<<4096, 256, 0, stream>>>(x,  xb, 1048576);
  cvt_kernel<<<4096, 256, 0, stream>>>(wq, wb, 1048576);
  cvt_kernel<<<1024, 256, 0, stream>>>(wk, wb + (size_t)2048 * 2048, 262144);
  cvt_kernel<<<1024, 256, 0, stream>>>(wv, wb + (size_t)2560 * 2048, 262144);
  // 2) fused QKV projection (128x96 tile -> 512 blocks = 2/CU exactly, all-bf16, dbuf)
  gemm_db<128, 96, 1><<<dim3(32, 16), 256, 0, stream>>>(xb, wb, qkv, LDQ, 2048, 2048);
  // 3) wo -> bf16 (wb region dead now)
  cvt_kernel<<<4096, 256, 0, stream>>>(wo, wob, 1048576);
  // 4) RoPE: q pre-scaled by log2e/sqrt(HD); k unscaled
  rope_kernel<<<8192, 256, 0, stream>>>(qkv, fc, 5, LDQ, 0.18033688f);
  rope_kernel<<<2048, 256, 0, stream>>>(qkv + 2048, fc, 3, LDQ, 1.0f);
  // 5) V transpose
  transpose_v<<<4096, 256, 0, stream>>>(qkv, vTb);
  // 6) causal GQA flash attention -> ob (512 uniform blocks: pair p & 31-p per block)
  attn_kernel<<<dim3(NH, 16), 256, 0, stream>>>(qkv, vTb, ob);
  // 7) output projection (128x64, all-bf16, dbuf, fp32 out) — overwrites xb scratch
  gemm_db<128, 64, 0><<<dim3(32, 16), 256, 0, stream>>>(ob, wob, out, 2048, 2048, 2048);
}

// Round 3
// 231.797 us; speedup vs baseline: 1.0503x; 1.0087x over previous
//
#include <hip/hip_runtime.h>

typedef unsigned short u16;
typedef unsigned int u32;
typedef __bf16 bf16x8 __attribute__((ext_vector_type(8)));
typedef unsigned short ushort8 __attribute__((ext_vector_type(8)));
typedef float floatx4 __attribute__((ext_vector_type(4)));
typedef u32 u32x2 __attribute__((ext_vector_type(2)));

#define S_LEN 2048
#define NH 32
#define NKV 8
#define HD_ 64
#define LDQ 3072   // qkv row stride: [q 0..2047 | k 2048..2559 | v 2560..3071]

__device__ __forceinline__ u16 f2bf(float f) {
  unsigned u = __builtin_bit_cast(unsigned, f);
  u += 0x7FFF + ((u >> 16) & 1);   // round-to-nearest-even
  return (u16)(u >> 16);
}
__device__ __forceinline__ float bf2f(u16 h) {
  unsigned u = ((unsigned)h) << 16;
  return __builtin_bit_cast(float, u);
}
__device__ __forceinline__ bf16x8 ld8(const u16* p) {
  return __builtin_bit_cast(bf16x8, *(const ushort8*)p);
}
__device__ __forceinline__ floatx4 mfma16(bf16x8 a, bf16x8 b, floatx4 c) {
  return __builtin_amdgcn_mfma_f32_16x16x32_bf16(a, b, c, 0, 0, 0);
}
// two fp32 -> packed bf16 pair (round-half-up via +0x8000, then byte-perm)
__device__ __forceinline__ u32 pk2bf(float a, float b) {
  u32 ua = __builtin_bit_cast(u32, a) + 0x8000u;
  u32 ub = __builtin_bit_cast(u32, b) + 0x8000u;
  return __builtin_amdgcn_perm(ub, ua, 0x07060302);   // [bf(a) | bf(b)<<16]
}

// ---------------- fp32 -> bf16 convert (vectorized) ----------------
__global__ void cvt_kernel(const float* __restrict__ in, u16* __restrict__ out, int n4) {
  int i = blockIdx.x * blockDim.x + threadIdx.x;
  if (i >= n4) return;
  float4 v = ((const float4*)in)[i];
  ((ushort4*)out)[i] = make_ushort4(f2bf(v.x), f2bf(v.y), f2bf(v.z), f2bf(v.w));
}

// ---------------- Double-buffered GEMM: C[M][N] = A[M][K] @ B[N][K]^T (bf16 in) ------------
// TM x TN tile, BK=64, 4 waves (2x2). Single barrier per K-iter: while computing buf p,
// the next tile's global loads (issued at iter start) are ds_written into buf p^1; the
// vmcnt wait for them lands after the full compute phase. LDS chunk-XOR swizzle keeps
// all staging writes and fragment reads <=2 lanes/bank (conflict-free, measured 0).
// Occupancy note (r1): QKV retiled 128x128 -> 128x96 so grid = 512 blocks = exactly
// 2 blocks/CU (LDS 56KB x2 = 112KB < 160KB).
template <int TM, int TN, int OUT_BF16>
__global__ __launch_bounds__(256) void gemm_db(
    const u16* __restrict__ A, const u16* __restrict__ B, void* __restrict__ C,
    int ldc, int K, int lda) {
  __shared__ __align__(16) u16 As[2][TM * 64];
  __shared__ __align__(16) u16 Bs[2][TN * 64];
  const int tid = threadIdx.x;
  const int wave = tid >> 6, lane = tid & 63;
  const int quad = lane >> 4, l16 = lane & 15;
  const int bm = blockIdx.y * TM, bn = blockIdx.x * TN;
  const int wr = (wave >> 1) * (TM / 2), wc = (wave & 1) * (TN / 2);
  constexpr int MI = TM / 32, NI = TN / 32;
  const int crow = tid >> 3, col8 = tid & 7;     // staging: row base, 8-elem col chunk

  size_t aoff[MI], boff[NI];
#pragma unroll
  for (int j = 0; j < MI; j++) aoff[j] = (size_t)(bm + crow + j * 32) * lda + col8 * 8;
#pragma unroll
  for (int j = 0; j < NI; j++) boff[j] = (size_t)(bn + crow + j * 32) * K + col8 * 8;

  ushort8 a8[MI], b8[NI];
  auto load_tiles = [&](int k0) {
#pragma unroll
    for (int j = 0; j < MI; j++) a8[j] = *(const ushort8*)(A + aoff[j] + k0);
#pragma unroll
    for (int j = 0; j < NI; j++) b8[j] = *(const ushort8*)(B + boff[j] + k0);
  };
  auto write_tiles = [&](int p) {
#pragma unroll
    for (int j = 0; j < MI; j++) {
      const int row = crow + j * 32;
      *(ushort8*)&As[p][row * 64 + ((col8 ^ (row & 7)) * 8)] = a8[j];
    }
#pragma unroll
    for (int j = 0; j < NI; j++) {
      const int row = crow + j * 32;
      *(ushort8*)&Bs[p][row * 64 + ((col8 ^ (row & 7)) * 8)] = b8[j];
    }
  };

  floatx4 acc[MI][NI] = {};
  load_tiles(0);
  write_tiles(0);
  __syncthreads();
  int p = 0;
  for (int k0 = 0; k0 < K; k0 += 64) {
    const bool more = (k0 + 64 < K);
    if (more) load_tiles(k0 + 64);               // prefetch next tile (covered by compute)
#pragma unroll
    for (int kh = 0; kh < 2; kh++) {
      bf16x8 af[MI], bfr[NI];
#pragma unroll
      for (int mi = 0; mi < MI; mi++) {
        const int row = wr + mi * 16 + l16;
        af[mi] = ld8(&As[p][row * 64 + (((kh * 4 + quad) ^ (row & 7)) * 8)]);
      }
#pragma unroll
      for (int ni = 0; ni < NI; ni++) {
        const int row = wc + ni * 16 + l16;
        bfr[ni] = ld8(&Bs[p][row * 64 + (((kh * 4 + quad) ^ (row & 7)) * 8)]);
      }
#pragma unroll
      for (int mi = 0; mi < MI; mi++)
#pragma unroll
        for (int ni = 0; ni < NI; ni++)
          acc[mi][ni] = mfma16(af[mi], bfr[ni], acc[mi][ni]);
    }
    if (more) {
      write_tiles(p ^ 1);                        // vmcnt wait lands here, post-compute
      __syncthreads();                           // one barrier per iter
      p ^= 1;
    }
  }

#pragma unroll
  for (int mi = 0; mi < MI; mi++)
#pragma unroll
    for (int ni = 0; ni < NI; ni++)
#pragma unroll
      for (int r = 0; r < 4; r++) {
        const int row = bm + wr + mi * 16 + quad * 4 + r;   // C/D: row=(lane>>4)*4+reg
        const int col = bn + wc + ni * 16 + l16;            //      col=lane&15
        if (OUT_BF16) ((u16*)C)[(size_t)row * ldc + col] = f2bf(acc[mi][ni][r]);
        else          ((float*)C)[(size_t)row * ldc + col] = acc[mi][ni][r];
      }
}

// ---------------- RoPE in-place on bf16, rows of `row_stride`, nheads = 1<<h_bits ----------------
__global__ void rope_kernel(u16* __restrict__ qk, const float* __restrict__ fc, int h_bits,
                            int row_stride, float scale) {
  int idx = blockIdx.x * blockDim.x + threadIdx.x;   // over S * nheads * 32 pairs
  int d = idx & 31;
  int t = idx >> 5;
  int hh = t & ((1 << h_bits) - 1);
  int s = t >> h_bits;
  float c  = fc[s * 64 + d * 2];
  float sn = fc[s * 64 + d * 2 + 1];
  size_t base = (size_t)s * row_stride + hh * 64 + d * 2;
  float x0 = bf2f(qk[base]), x1 = bf2f(qk[base + 1]);
  qk[base]     = f2bf((x0 * c - x1 * sn) * scale);
  qk[base + 1] = f2bf((x0 * sn + x1 * c) * scale);
}

// ---------------- V transpose: qkv[s][2560 + g*64+hd] -> vT[(g*64+hd)][s] ----------------
__global__ void transpose_v(const u16* __restrict__ qkv, u16* __restrict__ vT) {
  int idx = blockIdx.x * blockDim.x + threadIdx.x;   // over KV*HD*S
  int s = idx & (S_LEN - 1);
  int t = idx >> 11;                                 // g*64+hd
  vT[idx] = qkv[(size_t)s * LDQ + 2560 + t];
}

// ---------------- Flash attention (causal, GQA), fused-pair, dbuf, swizzled LDS ------------
// r3: (a) stride-72 LDS was 8-way bank conflicted (36 dwords == 4 mod 32; 5.9M conflict
// cycles/dispatch = ~176 cy per block-iter). Replaced with the gemm's chunk-XOR stride-64
// layout (measured 0 conflicts there). (b) K/V double-buffered -> ONE barrier per iter.
// (c) q-tile pair (p, 31-p) fused into a single kt loop with two accumulator sets: A-tile
// active while kt<=p. Staging iters per block drop 33 -> 32-p (49/CU with the y-remap
// pairing complementary blocks 256 apart in dispatch order), V-frags read once per iter
// serve both PV steps, and independent A/B MFMA chains double per-iter ILP.
__global__ __launch_bounds__(256) void attn_kernel(const u16* qkv, const u16* __restrict__ vT,
                                                   u16* __restrict__ o) {
  __shared__ __align__(16) u16 Ks[2][64 * 64];   // [key][hd], chunk-XOR swizzled
  __shared__ __align__(16) u16 Vs[2][64 * 64];   // [hd][key], chunk-XOR swizzled
  __shared__ __align__(16) u16 pS[8][16 * 64];   // per-wave P^T scratch: wave w -> A=pS[w], B=pS[w+4]
  const int h = blockIdx.x;
  const int g = h >> 2;                          // kv head
  const int tid = threadIdx.x;
  const int wave = tid >> 6, lane = tid & 63;
  const int quad = lane >> 4, l16 = lane & 15;
  const int y = (int)blockIdx.y;                 // 0..15
  const int p_ = (y < 8) ? y : 23 - y;           // blocks 256 apart in dispatch get p, 15-p
  const int qlo = p_, qhi = 31 - p_;             // fused q-tile pair; iters = 32-p_

  const ushort8 ones_u = {0x3F80, 0x3F80, 0x3F80, 0x3F80, 0x3F80, 0x3F80, 0x3F80, 0x3F80};
  const bf16x8 onesA = __builtin_bit_cast(bf16x8, ones_u);

  const int qrow = wave * 16 + l16;
  const int qgA = qlo * 64 + qrow, qgB = qhi * 64 + qrow;
  const size_t qoffA = (size_t)qgA * LDQ + h * HD_;
  const size_t qoffB = (size_t)qgB * LDQ + h * HD_;
  bf16x8 qfA0 = ld8(qkv + qoffA + quad * 8);     // B-frag: n=q, k=hd (pre-scaled log2e/8)
  bf16x8 qfA1 = ld8(qkv + qoffA + 32 + quad * 8);
  bf16x8 qfB0 = ld8(qkv + qoffB + quad * 8);
  bf16x8 qfB1 = ld8(qkv + qoffB + 32 + quad * 8);

  // staging: 512 chunks of 16B per tile; thread t owns rows {r0, r0+32}, chunk col8.
  // swizzled chunk slot: col8 ^ (row&7); r0 and r0+32 share (row&7) -> same slot offset.
  const int r0 = tid >> 3, r1 = r0 + 32;
  const int col8 = tid & 7;
  const int so = (col8 ^ (r0 & 7)) * 8;          // swizzled u16 offset within row
  const int o0 = col8 * 8;                       // global col offset
  const u16* ksrc = qkv + 2048 + g * HD_;        // row stride LDQ
  const u16* vsrc = vT + (size_t)g * HD_ * S_LEN;// row stride S_LEN

  ushort8 kp0 = *(const ushort8*)(ksrc + (size_t)r0 * LDQ + o0);
  ushort8 kp1 = *(const ushort8*)(ksrc + (size_t)r1 * LDQ + o0);
  ushort8 vp0 = *(const ushort8*)(vsrc + (size_t)r0 * S_LEN + o0);
  ushort8 vp1 = *(const ushort8*)(vsrc + (size_t)r1 * S_LEN + o0);

  floatx4 OA[4] = {}, OB[4] = {};                // O^T: row=hd(nt*16+quad*4+r), col=q(l16)
  floatx4 lA = {}, lB = {};                      // l via MFMA ones-row
  u16* myPA = &pS[wave][0];
  u16* myPB = &pS[wave + 4][0];

  // prologue: stage tile 0 into buf 0, prefetch tile 1 (qhi >= 16 so it exists)
  *(ushort8*)&Ks[0][r0 * 64 + so] = kp0;
  *(ushort8*)&Ks[0][r1 * 64 + so] = kp1;
  *(ushort8*)&Vs[0][r0 * 64 + so] = vp0;
  *(ushort8*)&Vs[0][r1 * 64 + so] = vp1;
  kp0 = *(const ushort8*)(ksrc + (size_t)(64 + r0) * LDQ + o0);
  kp1 = *(const ushort8*)(ksrc + (size_t)(64 + r1) * LDQ + o0);
  vp0 = *(const ushort8*)(vsrc + (size_t)r0 * S_LEN + 64 + o0);
  vp1 = *(const ushort8*)(vsrc + (size_t)r1 * S_LEN + 64 + o0);
  __syncthreads();
  int pp = 0;

  for (int kt = 0; kt <= qhi; kt++) {
    const int kbase = kt * 64;
    const bool more = kt < qhi;
    if (more) {                                  // stage tile kt+1 into buf pp^1 (regs ready)
      *(ushort8*)&Ks[pp ^ 1][r0 * 64 + so] = kp0;
      *(ushort8*)&Ks[pp ^ 1][r1 * 64 + so] = kp1;
      *(ushort8*)&Vs[pp ^ 1][r0 * 64 + so] = vp0;
      *(ushort8*)&Vs[pp ^ 1][r1 * 64 + so] = vp1;
      if (kt + 1 < qhi) {                        // prefetch tile kt+2 (covered by compute)
        const int nb = kbase + 128;
        kp0 = *(const ushort8*)(ksrc + (size_t)(nb + r0) * LDQ + o0);
        kp1 = *(const ushort8*)(ksrc + (size_t)(nb + r1) * LDQ + o0);
        vp0 = *(const ushort8*)(vsrc + (size_t)r0 * S_LEN + nb + o0);
        vp1 = *(const ushort8*)(vsrc + (size_t)r1 * S_LEN + nb + o0);
      }
    }
    const u16* Kc = &Ks[pp][0];
    const u16* Vc = &Vs[pp][0];
    const bool actA = (kt <= qlo);

    // ---- S^T = K*Q^T for B (and A while active): 4 sub-tiles of 16 keys ----
    floatx4 sfA[4], sfB[4];
#pragma unroll
    for (int sub = 0; sub < 4; sub++) {
      const int row = sub * 16 + l16;            // row&7 == l16&7
      const u16* kb = Kc + row * 64;
      bf16x8 k0 = ld8(kb + ((quad ^ (l16 & 7)) * 8));
      bf16x8 k1 = ld8(kb + (((4 + quad) ^ (l16 & 7)) * 8));
      floatx4 sB = {};
      sB = mfma16(k0, qfB0, sB);                 // A-frag: m=key, k=hd
      sB = mfma16(k1, qfB1, sB);
      sfB[sub] = sB;
      if (actA) {
        floatx4 sA = {};
        sA = mfma16(k0, qfA0, sA);
        sA = mfma16(k1, qfA1, sA);
        sfA[sub] = sA;
      }
    }
    if (kt == qhi) {                             // B diagonal tile: mask key > q
#pragma unroll
      for (int sub = 0; sub < 4; sub++)
#pragma unroll
        for (int r = 0; r < 4; r++)
          if (kbase + sub * 16 + quad * 4 + r > qgB) sfB[sub][r] = -INFINITY;
    }
    if (kt == qlo) {                             // A diagonal tile
#pragma unroll
      for (int sub = 0; sub < 4; sub++)
#pragma unroll
        for (int r = 0; r < 4; r++)
          if (kbase + sub * 16 + quad * 4 + r > qgA) sfA[sub][r] = -INFINITY;
    }

    // ---- P = exp2(s'), pack to bf16 pairs ----
    u32x2 pkA[4], pkB[4];
#pragma unroll
    for (int sub = 0; sub < 4; sub++) {
      pkB[sub].x = pk2bf(__builtin_amdgcn_exp2f(sfB[sub][0]), __builtin_amdgcn_exp2f(sfB[sub][1]));
      pkB[sub].y = pk2bf(__builtin_amdgcn_exp2f(sfB[sub][2]), __builtin_amdgcn_exp2f(sfB[sub][3]));
      if (actA) {
        pkA[sub].x = pk2bf(__builtin_amdgcn_exp2f(sfA[sub][0]), __builtin_amdgcn_exp2f(sfA[sub][1]));
        pkA[sub].y = pk2bf(__builtin_amdgcn_exp2f(sfA[sub][2]), __builtin_amdgcn_exp2f(sfA[sub][3]));
      }
    }

    // ---- V frags from LDS (read once, used for both PV steps) ----
    bf16x8 vf[4][2];
#pragma unroll
    for (int nt = 0; nt < 4; nt++) {
      const u16* vb = Vc + (nt * 16 + l16) * 64;
      vf[nt][0] = ld8(vb + ((quad ^ (l16 & 7)) * 8));
      vf[nt][1] = ld8(vb + (((4 + quad) ^ (l16 & 7)) * 8));
    }

    // ---- P^T to per-wave LDS scratch (swizzled b64 stores, <=2 lanes/bank) ----
#pragma unroll
    for (int sub = 0; sub < 4; sub++) {
      const int slot = (2 * sub + (quad >> 1)) ^ (l16 & 7);
      const int a = l16 * 64 + slot * 8 + (quad & 1) * 4;
      *(u32x2*)&myPB[a] = pkB[sub];
      if (actA) *(u32x2*)&myPA[a] = pkA[sub];
    }
    asm volatile("s_waitcnt lgkmcnt(0)" ::: "memory");  // wave-local LDS write->read fence
    bf16x8 pB0 = ld8(&myPB[l16 * 64 + ((quad ^ (l16 & 7)) * 8)]);        // key 0..31
    bf16x8 pB1 = ld8(&myPB[l16 * 64 + (((4 + quad) ^ (l16 & 7)) * 8)]);  // key 32..63
    // ---- O^T += V^T * P^T ; l += ones * P^T (matrix pipe) ----
#pragma unroll
    for (int nt = 0; nt < 4; nt++) {
      OB[nt] = mfma16(vf[nt][0], pB0, OB[nt]);
      OB[nt] = mfma16(vf[nt][1], pB1, OB[nt]);
    }
    lB = mfma16(onesA, pB0, lB);
    lB = mfma16(onesA, pB1, lB);
    if (actA) {
      bf16x8 pA0 = ld8(&myPA[l16 * 64 + ((quad ^ (l16 & 7)) * 8)]);
      bf16x8 pA1 = ld8(&myPA[l16 * 64 + (((4 + quad) ^ (l16 & 7)) * 8)]);
#pragma unroll
      for (int nt = 0; nt < 4; nt++) {
        OA[nt] = mfma16(vf[nt][0], pA0, OA[nt]);
        OA[nt] = mfma16(vf[nt][1], pA1, OA[nt]);
      }
      lA = mfma16(onesA, pA0, lA);
      lA = mfma16(onesA, pA1, lA);
    }
    if (more) {
      __syncthreads();                           // single barrier per iter (dbuf)
      pp ^= 1;
    }
  }

  const float invA = 1.0f / lA[0];
  const float invB = 1.0f / lB[0];
  const size_t ooffA = (size_t)qgA * 2048 + h * HD_;
  const size_t ooffB = (size_t)qgB * 2048 + h * HD_;
#pragma unroll
  for (int nt = 0; nt < 4; nt++)
#pragma unroll
    for (int r = 0; r < 4; r++) {
      const int hd = nt * 16 + quad * 4 + r;
      o[ooffA + hd] = f2bf(OA[nt][r] * invA);
      o[ooffB + hd] = f2bf(OB[nt][r] * invB);
    }
}

extern "C" void kernel_launch(void* const* d_in, const int* in_sizes, int n_in,
                              void* d_out, int out_size, void* d_ws, size_t ws_size,
                              hipStream_t stream) {
  const float* x  = (const float*)d_in[0];
  const float* fc = (const float*)d_in[1];
  const float* wq = (const float*)d_in[2];
  const float* wk = (const float*)d_in[3];
  const float* wv = (const float*)d_in[4];
  const float* wo = (const float*)d_in[5];
  float* out = (float*)d_out;

  // Workspace (30 MB — r3-proven size). Lifetimes:
  //   [0,12)MB  qkv bf16: 2048 x 3072 (q|k|v), written by QKV gemm, read-only after rope
  //   [12,24)MB wb bf16: wq|wk|wv (3072 x 2048) — dead after QKV gemm
  //   [12,14)MB vT bf16 (after wb dead)
  //   [14,22)MB wob bf16 (cvt'd after QKV gemm)
  //   [22,30)MB ob bf16: attention output
  // x bf16 (8 MB) lives in d_out (16.8 MB) — overwritten by the final O-GEMM.
  char* ws = (char*)d_ws;
  const size_t MB = 1024 * 1024;
  u16* qkv = (u16*)(ws);
  u16* wb  = (u16*)(ws + 12 * MB);
  u16* vTb = (u16*)(ws + 12 * MB);
  u16* wob = (u16*)(ws + 14 * MB);
  u16* ob  = (u16*)(ws + 22 * MB);
  u16* xb  = (u16*)d_out;
  (void)ws_size; (void)n_in; (void)in_sizes; (void)out_size;

  // 1) x, wq|wk|wv -> bf16
  cvt_kernel<<<4096, 256, 0, stream>>>(x,  xb, 1048576);
  cvt_kernel<<<4096, 256, 0, stream>>>(wq, wb, 1048576);
  cvt_kernel<<<1024, 256, 0, stream>>>(wk, wb + (size_t)2048 * 2048, 262144);
  cvt_kernel<<<1024, 256, 0, stream>>>(wv, wb + (size_t)2560 * 2048, 262144);
  // 2) fused QKV projection (128x96 tile -> 512 blocks = 2/CU exactly, all-bf16, dbuf)
  gemm_db<128, 96, 1><<<dim3(32, 16), 256, 0, stream>>>(xb, wb, qkv, LDQ, 2048, 2048);
  // 3) wo -> bf16 (wb region dead now)
  cvt_kernel<<<4096, 256, 0, stream>>>(wo, wob, 1048576);
  // 4) RoPE: q pre-scaled by log2e/sqrt(HD); k unscaled
  rope_kernel<<<8192, 256, 0, stream>>>(qkv, fc, 5, LDQ, 0.18033688f);
  rope_kernel<<<2048, 256, 0, stream>>>(qkv + 2048, fc, 3, LDQ, 1.0f);
  // 5) V transpose
  transpose_v<<<4096, 256, 0, stream>>>(qkv, vTb);
  // 6) causal GQA flash attention -> ob (512 blocks; block = fused q-tile pair p,31-p)
  attn_kernel<<<dim3(NH, 16), 256, 0, stream>>>(qkv, vTb, ob);
  // 7) output projection (128x64, all-bf16, dbuf, fp32 out) — overwrites xb scratch
  gemm_db<128, 64, 0><<<dim3(32, 16), 256, 0, stream>>>(ob, wob, out, 2048, 2048, 2048);
}